// Round 23
// baseline (450.808 us; speedup 1.0000x reference)
//
#include <hip/hip_runtime.h>

#define HW 112
#define PP 12544
#define BB 4
#define RR 49
#define RS 256
#define GW 114          // padded grid width (zero ring)
#define GP (GW*GW)      // 12996
#define CK 160          // padded channels for conv0

typedef __bf16 bf16;
typedef __bf16 bf16x8 __attribute__((ext_vector_type(8)));
typedef __bf16 bf16x4 __attribute__((ext_vector_type(4)));
typedef float f32x4 __attribute__((ext_vector_type(4)));

// XOR-swizzled byte offset in a row-major bf16 tile; rowbytes ∈ {128,256,512}
__device__ __forceinline__ int swzg(int row, int halfcol, int rowbytes) {
  int byte = halfcol * 2;
  return row * rowbytes + (byte & ~127) + ((((byte >> 4) ^ row) & 7) * 16) + (byte & 15);
}
__device__ __forceinline__ int swz128(int row, int halfcol) { return swzg(row, halfcol, 128); }

// tanh-approx gelu (max abs err ~3e-4 vs exact erf form)
__device__ __forceinline__ float gelu_fast(float x) {
  float y = 0.7978845608f * (x + 0.044715f * x * x * x);
  float t = __expf(-2.f * fabsf(y));
  float th = (1.f - t) / (1.f + t);
  th = copysignf(th, y);
  return 0.5f * x * (1.f + th);
}

// async global->LDS (no VGPR round-trip). LDS dest = wave-uniform base + lane*size.
__device__ __forceinline__ void gl_lds16(const void* g, void* l) {
  __builtin_amdgcn_global_load_lds((const __attribute__((address_space(1))) unsigned int*)g,
                                   (__attribute__((address_space(3))) unsigned int*)l, 16, 0, 0);
}
__device__ __forceinline__ void gl_lds4(const void* g, void* l) {
  __builtin_amdgcn_global_load_lds((const __attribute__((address_space(1))) unsigned int*)g,
                                   (__attribute__((address_space(3))) unsigned int*)l, 4, 0, 0);
}

// ---------------- merged setup: ring-zero + conv0-weight transpose + bulk f32->bf16 ----------------
__global__ __launch_bounds__(256) void k_setup(bf16* __restrict__ xct,
    const float* __restrict__ c0w, bf16* __restrict__ wTb,
    const float* __restrict__ s0, bf16* __restrict__ d0,
    const float* __restrict__ s1, bf16* __restrict__ d1,
    const float* __restrict__ s2, bf16* __restrict__ d2,
    const float* __restrict__ s3, bf16* __restrict__ d3) {
  int b = blockIdx.x;
  int tid = threadIdx.x;
  if (b < 142) {
    // zero only the 1-pixel ring of xct: 4*452*20 = 36160 uint4s
    int t = b * 256 + tid;
    if (t >= BB * 452 * 20) return;
    int c4 = t % 20; int rem = t / 20; int ri = rem % 452; int n = rem / 452;
    int hh, ww;
    if (ri < 114)      { hh = 0;   ww = ri; }
    else if (ri < 228) { hh = 113; ww = ri - 114; }
    else if (ri < 340) { hh = 1 + (ri - 228); ww = 0; }
    else               { hh = 1 + (ri - 340); ww = 113; }
    uint4 zz = {0, 0, 0, 0};
    *(uint4*)(xct + ((size_t)n * GP + hh * GW + ww) * CK + c4 * 8) = zz;
  } else if (b < 502) {
    // conv0 weights -> wTb bf16 [9tap][5ks][64o][32c]
    int t = (b - 142) * 256 + tid;
    if (t >= 9 * 5 * 64 * 32) return;
    int cc = t & 31; int o = (t >> 5) & 63; int ks = (t >> 11) % 5; int k = t / 10240;
    int c = ks * 32 + cc;
    wTb[t] = (bf16)((c < 131) ? c0w[((size_t)(o * 131) + c) * 9 + k] : 0.f);
  } else {
    // bulk f32->bf16 weight conversion (qkv, proj, fc1, fc2)
    int t = (b - 502) * 256 + tid;
    if (t < 49152) { d0[t] = (bf16)s0[t]; return; }
    t -= 49152;
    if (t < 16384) { d1[t] = (bf16)s1[t]; return; }
    t -= 16384;
    if (t < 65536) { d2[t] = (bf16)s2[t]; return; }
    t -= 65536;
    if (t < 65536) { d3[t] = (bf16)s3[t]; }
  }
}

// ---------------- prep: downsample+concat -> xcat_t bf16 [n][grid 114x114][160], mask ----------------
__global__ __launch_bounds__(256) void k_prep2(const float* __restrict__ ex0, const float* __restrict__ ex,
    const float* __restrict__ img, const float* __restrict__ pre,
    bf16* __restrict__ xct, float* __restrict__ maskr) {
  __shared__ bf16 sT2[64 * 168];
  int n = blockIdx.y;
  int p0 = blockIdx.x * 64;
  int tid = threadIdx.x;
  uint4 zz = {0, 0, 0, 0};
  for (int i2 = tid; i2 < 1344; i2 += 256) ((uint4*)sT2)[i2] = zz;
  __syncthreads();
  int l = tid & 63, g = tid >> 6;
  int p = p0 + l;
  int h = p / HW, w = p % HW;
  for (int c = g; c < 131; c += 4) {
    float val;
    if (c < 64) {
      const float* s = ex0 + (((size_t)(n * 64 + c)) * 224 + 2 * h) * 224 + 2 * w;
      val = 0.5f * (0.5f * (s[0] + s[224]) + 0.5f * (s[1] + s[225]));
    } else if (c < 128) {
      val = ex[((size_t)(n * 64 + (c - 64))) * PP + p];
    } else {
      const float* s = img + (((size_t)(n * 3 + (c - 128))) * 224 + 2 * h) * 224 + 2 * w;
      val = 0.5f * (0.5f * (s[0] + s[224]) + 0.5f * (s[1] + s[225]));
    }
    sT2[l * 168 + c] = (bf16)val;
  }
  if (tid < 64) {
    const float* s = pre + ((size_t)n * 224 + 2 * h) * 224 + 2 * w;
    float v = 0.5f * (0.5f * (s[0] + s[224]) + 0.5f * (s[1] + s[225]));
    int r = (h >> 4) * 7 + (w >> 4); int sIdx = (h & 15) * 16 + (w & 15);
    maskr[(n * RR + r) * RS + sIdx] = (v > 0.0f) ? 0.0f : -100.0f;
  }
  __syncthreads();
  for (int i2 = tid; i2 < 1280; i2 += 256) {
    int row = i2 / 20, ch = i2 % 20;
    int pr = p0 + row;
    int hh = pr / HW, ww = pr % HW;
    uint4 d = *(const uint4*)(sT2 + row * 168 + ch * 8);
    *(uint4*)(xct + ((size_t)n * GP + (hh + 1) * GW + ww + 1) * CK + ch * 8) = d;
  }
}

// ---------------- conv0 as MFMA implicit GEMM ----------------
__global__ __launch_bounds__(256) void k_conv0m(const bf16* __restrict__ xct, const bf16* __restrict__ wTb,
    const float* __restrict__ bias, float* __restrict__ out_t) {
  __shared__ bf16 sA[128 * 32];
  __shared__ bf16 sB[64 * 32];
  int n = blockIdx.y;
  int p0 = blockIdx.x * 128;
  int tid = threadIdx.x, lane = tid & 63, wv = tid >> 6;
  int lo = lane & 15, hi = lane >> 4;
  size_t gofsA[2];
  #pragma unroll
  for (int it = 0; it < 2; it++) {
    int idx = tid + it * 256;
    int row = idx >> 2, ch = idx & 3;
    int p = p0 + row;
    int hh = p / HW, ww = p % HW;
    gofsA[it] = ((size_t)(hh + 1) * GW + ww + 1) * (CK * 2) + ch * 16;
  }
  const char* xbase = (const char*)(xct + (size_t)n * GP * CK);
  f32x4 acc[2][4];
  #pragma unroll
  for (int mi = 0; mi < 2; mi++)
    #pragma unroll
    for (int ni = 0; ni < 4; ni++) acc[mi][ni] = (f32x4){0.f, 0.f, 0.f, 0.f};
  for (int tap = 0; tap < 9; tap++) {
    long shift = (long)((tap / 3 - 1) * GW + (tap % 3 - 1)) * (CK * 2);
    for (int ks = 0; ks < 5; ks++) {
      uint4 a0 = *(const uint4*)(xbase + gofsA[0] + shift + ks * 64);
      uint4 a1 = *(const uint4*)(xbase + gofsA[1] + shift + ks * 64);
      uint4 b0 = *(const uint4*)((const char*)wTb + ((size_t)(tap * 5 + ks) * 2048 + tid * 8) * 2);
      __syncthreads();
      *(uint4*)((char*)sA + tid * 16) = a0;
      *(uint4*)((char*)sA + (tid + 256) * 16) = a1;
      *(uint4*)((char*)sB + tid * 16) = b0;
      __syncthreads();
      bf16x8 aF[2], bF[4];
      #pragma unroll
      for (int mi = 0; mi < 2; mi++)
        aF[mi] = *(const bf16x8*)((const char*)sA + (wv * 32 + mi * 16 + lo) * 64 + hi * 16);
      #pragma unroll
      for (int ni = 0; ni < 4; ni++)
        bF[ni] = *(const bf16x8*)((const char*)sB + (ni * 16 + lo) * 64 + hi * 16);
      #pragma unroll
      for (int mi = 0; mi < 2; mi++)
        #pragma unroll
        for (int ni = 0; ni < 4; ni++)
          acc[mi][ni] = __builtin_amdgcn_mfma_f32_16x16x32_bf16(aF[mi], bF[ni], acc[mi][ni], 0, 0, 0);
    }
  }
  #pragma unroll
  for (int ni = 0; ni < 4; ni++) {
    float bv = bias[ni * 16 + lo];
    #pragma unroll
    for (int mi = 0; mi < 2; mi++) {
      #pragma unroll
      for (int r2 = 0; r2 < 4; r2++) {
        int p = p0 + wv * 32 + mi * 16 + hi * 4 + r2;
        out_t[((size_t)n * PP + p) * 64 + ni * 16 + lo] = acc[mi][ni][r2] + bv;
      }
    }
  }
}

// ---------------- fused region qkv (8 waves): LN1 + single-stage weights + 3 barrier-free GEMMs ----------------
// qd/kd layout: [n][r][64] (row-contiguous)
__global__ __launch_bounds__(512) void k_qkvr(const float* __restrict__ xin, const float* __restrict__ lng,
    const float* __restrict__ lnb, const bf16* __restrict__ wb, const float* __restrict__ bias,
    bf16* __restrict__ qRo, bf16* __restrict__ kRo, bf16* __restrict__ vto, bf16* __restrict__ vTo,
    float* __restrict__ qd, float* __restrict__ kd) {
  __shared__ __align__(16) char smem[61440];
  bf16* sA = (bf16*)smem;               // 256x64 tile, 32768B
  bf16* sB = (bf16*)(smem + 32768);     // 192x64 weights, 24576B
  float* rq = (float*)(smem + 57344);   // [8][64] 2048B
  float* rk = (float*)(smem + 59392);   // [8][64] 2048B
  bf16* sT = (bf16*)smem;               // overlay for vT transpose (64x264)
  int r = blockIdx.x, n = blockIdx.y;
  int nr = n * RR + r;
  int rh = (r / 7) * 16, rw = (r % 7) * 16;
  int tid = threadIdx.x, lane = tid & 63, wv = tid >> 6;
  int lo = lane & 15, hi = lane >> 4;
  { // LN staging: 2 threads per pixel-row, single pass
    int row = tid >> 1, part = tid & 1;
    int y = row >> 4, x = row & 15;
    const float* xp = xin + ((size_t)n * PP + (rh + y) * HW + rw + x) * 64 + part * 32;
    float v[32]; float s = 0.f, sq = 0.f;
    #pragma unroll
    for (int i = 0; i < 8; i++) {
      float4 d = *(const float4*)&xp[i * 4];
      v[i*4]=d.x; v[i*4+1]=d.y; v[i*4+2]=d.z; v[i*4+3]=d.w;
      s += d.x+d.y+d.z+d.w;
      sq += d.x*d.x+d.y*d.y+d.z*d.z+d.w*d.w;
    }
    s += __shfl_xor(s, 1, 64); sq += __shfl_xor(sq, 1, 64);
    float mu = s * (1.f/64.f);
    float rstd = rsqrtf(fmaxf(sq * (1.f/64.f) - mu*mu, 0.f) + 1e-5f);
    #pragma unroll
    for (int j2 = 0; j2 < 4; j2++) {
      bf16x8 o8;
      #pragma unroll
      for (int e = 0; e < 8; e++) {
        int c = part*32 + j2*8 + e;
        o8[e] = (bf16)((v[j2*8+e] - mu) * rstd * lng[c] + lnb[c]);
      }
      *(bf16x8*)((char*)sA + swz128(row, part*32 + j2*8)) = o8;
    }
  }
  { // stage ALL qkv weights: 1536 uint4 = 3/thread
    #pragma unroll
    for (int it = 0; it < 3; it++) {
      int idx = tid + it * 512;
      int oo = idx >> 3, q8 = idx & 7;
      uint4 d = *(const uint4*)(wb + (size_t)oo * 64 + q8 * 8);
      *(uint4*)((char*)sB + swz128(oo, q8 * 8)) = d;
    }
  }
  __syncthreads();
  // ---- ob0: q ----
  {
    f32x4 acc[2][4];
    #pragma unroll
    for (int mi = 0; mi < 2; mi++)
      #pragma unroll
      for (int ni = 0; ni < 4; ni++) acc[mi][ni] = (f32x4){0.f, 0.f, 0.f, 0.f};
    #pragma unroll
    for (int kk = 0; kk < 2; kk++) {
      bf16x8 aF[2], bF[4];
      #pragma unroll
      for (int mi = 0; mi < 2; mi++)
        aF[mi] = *(const bf16x8*)((const char*)sA + swz128(wv * 32 + mi * 16 + lo, kk * 32 + hi * 8));
      #pragma unroll
      for (int ni = 0; ni < 4; ni++)
        bF[ni] = *(const bf16x8*)((const char*)sB + swz128(ni * 16 + lo, kk * 32 + hi * 8));
      #pragma unroll
      for (int mi = 0; mi < 2; mi++)
        #pragma unroll
        for (int ni = 0; ni < 4; ni++)
          acc[mi][ni] = __builtin_amdgcn_mfma_f32_16x16x32_bf16(aF[mi], bF[ni], acc[mi][ni], 0, 0, 0);
    }
    float part_[4] = {0.f, 0.f, 0.f, 0.f};
    #pragma unroll
    for (int ni = 0; ni < 4; ni++) {
      float bv = bias[ni * 16 + lo];
      #pragma unroll
      for (int mi = 0; mi < 2; mi++) {
        #pragma unroll
        for (int r2 = 0; r2 < 4; r2++) {
          float rv = acc[mi][ni][r2] + bv;
          int s = wv * 32 + mi * 16 + hi * 4 + r2;
          qRo[((size_t)nr * RS + s) * 64 + ni * 16 + lo] = (bf16)(rv * 0.125f);
          part_[ni] += rv;
        }
      }
      part_[ni] += __shfl_xor(part_[ni], 16, 64);
      part_[ni] += __shfl_xor(part_[ni], 32, 64);
      if (hi == 0) rq[wv * 64 + ni * 16 + lo] = part_[ni];
    }
  }
  // ---- ob1: k ----
  {
    f32x4 acc[2][4];
    #pragma unroll
    for (int mi = 0; mi < 2; mi++)
      #pragma unroll
      for (int ni = 0; ni < 4; ni++) acc[mi][ni] = (f32x4){0.f, 0.f, 0.f, 0.f};
    #pragma unroll
    for (int kk = 0; kk < 2; kk++) {
      bf16x8 aF[2], bF[4];
      #pragma unroll
      for (int mi = 0; mi < 2; mi++)
        aF[mi] = *(const bf16x8*)((const char*)sA + swz128(wv * 32 + mi * 16 + lo, kk * 32 + hi * 8));
      #pragma unroll
      for (int ni = 0; ni < 4; ni++)
        bF[ni] = *(const bf16x8*)((const char*)sB + swz128(64 + ni * 16 + lo, kk * 32 + hi * 8));
      #pragma unroll
      for (int mi = 0; mi < 2; mi++)
        #pragma unroll
        for (int ni = 0; ni < 4; ni++)
          acc[mi][ni] = __builtin_amdgcn_mfma_f32_16x16x32_bf16(aF[mi], bF[ni], acc[mi][ni], 0, 0, 0);
    }
    float part_[4] = {0.f, 0.f, 0.f, 0.f};
    #pragma unroll
    for (int ni = 0; ni < 4; ni++) {
      float bv = bias[64 + ni * 16 + lo];
      #pragma unroll
      for (int mi = 0; mi < 2; mi++) {
        #pragma unroll
        for (int r2 = 0; r2 < 4; r2++) {
          float rv = acc[mi][ni][r2] + bv;
          int s = wv * 32 + mi * 16 + hi * 4 + r2;
          kRo[((size_t)nr * RS + s) * 64 + ni * 16 + lo] = (bf16)rv;
          part_[ni] += rv;
        }
      }
      part_[ni] += __shfl_xor(part_[ni], 16, 64);
      part_[ni] += __shfl_xor(part_[ni], 32, 64);
      if (hi == 0) rk[wv * 64 + ni * 16 + lo] = part_[ni];
    }
  }
  // ---- ob2: v ----
  {
    f32x4 acc[2][4];
    #pragma unroll
    for (int mi = 0; mi < 2; mi++)
      #pragma unroll
      for (int ni = 0; ni < 4; ni++) acc[mi][ni] = (f32x4){0.f, 0.f, 0.f, 0.f};
    #pragma unroll
    for (int kk = 0; kk < 2; kk++) {
      bf16x8 aF[2], bF[4];
      #pragma unroll
      for (int mi = 0; mi < 2; mi++)
        aF[mi] = *(const bf16x8*)((const char*)sA + swz128(wv * 32 + mi * 16 + lo, kk * 32 + hi * 8));
      #pragma unroll
      for (int ni = 0; ni < 4; ni++)
        bF[ni] = *(const bf16x8*)((const char*)sB + swz128(128 + ni * 16 + lo, kk * 32 + hi * 8));
      #pragma unroll
      for (int mi = 0; mi < 2; mi++)
        #pragma unroll
        for (int ni = 0; ni < 4; ni++)
          acc[mi][ni] = __builtin_amdgcn_mfma_f32_16x16x32_bf16(aF[mi], bF[ni], acc[mi][ni], 0, 0, 0);
    }
    float vreg[4][2][4];
    #pragma unroll
    for (int ni = 0; ni < 4; ni++) {
      float bv = bias[128 + ni * 16 + lo];
      int ch = ni * 16 + lo;
      #pragma unroll
      for (int mi = 0; mi < 2; mi++) {
        #pragma unroll
        for (int r2 = 0; r2 < 4; r2++) {
          float rv = acc[mi][ni][r2] + bv;
          vreg[ni][mi][r2] = rv;
          int s = wv * 32 + mi * 16 + hi * 4 + r2;
          vto[((size_t)n * PP + (rh + (s >> 4)) * HW + rw + (s & 15)) * 64 + ch] = (bf16)rv;
        }
      }
    }
    __syncthreads();   // all waves done reading sA/sB -> safe to overlay sT
    #pragma unroll
    for (int ni = 0; ni < 4; ni++) {
      int ch = ni * 16 + lo;
      #pragma unroll
      for (int mi = 0; mi < 2; mi++) {
        #pragma unroll
        for (int r2 = 0; r2 < 4; r2++) {
          int s = wv * 32 + mi * 16 + hi * 4 + r2;
          sT[ch * 264 + s] = (bf16)vreg[ni][mi][r2];
        }
      }
    }
    __syncthreads();
    #pragma unroll
    for (int it = 0; it < 4; it++) {
      int idx = tid + it * 512;
      int row = idx >> 5, ch8 = idx & 31;
      uint4 d = *(const uint4*)(sT + row * 264 + ch8 * 8);
      *(uint4*)(vTo + ((size_t)nr * 64 + row) * 256 + ch8 * 8) = d;
    }
    if (tid < 64) {
      int c = tid;
      float aq = 0.f, ak = 0.f;
      #pragma unroll
      for (int w8 = 0; w8 < 8; w8++) { aq += rq[w8 * 64 + c]; ak += rk[w8 * 64 + c]; }
      qd[(size_t)nr * 64 + c] = aq * (1.f / 256.f);
      kd[(size_t)nr * 64 + c] = ak * (1.f / 256.f);
    }
  }
}

// ---------------- gathered-region flash attention: 8-wave, inline top-4 (row-contiguous qd/kd), defer-max ----------------
__global__ __launch_bounds__(512, 6) void k_attn(const bf16* __restrict__ qR, const bf16* __restrict__ kR,
    const bf16* __restrict__ vT, const float* __restrict__ maskr,
    const float* __restrict__ qd, const float* __restrict__ kd,
    bf16* __restrict__ attnRb) {
  __shared__ bf16 sKd[2][64 * 64];
  __shared__ bf16 sVd[2][64 * 64];
  __shared__ bf16 sP[8][16 * 64];
  __shared__ float sMaskB[2][64];
  int bid = blockIdx.x;
  int newid = (bid & 7) * 49 + (bid >> 3);   // 392 = 8*49: bijective XCD chunking
  int n = newid / (RR * 2); int rem = newid % (RR * 2); int r = rem >> 1, qsp = rem & 1;
  int tid = threadIdx.x, lane = tid & 63, wv = tid >> 6;
  int lo = lane & 15, hi = lane >> 4;
  // ---- inline top-4 routing: qd/kd are [n][r][64] row-contiguous; scalar add order c=0..63
  //      identical to the original k_topk -> bit-identical routing ----
  int j0g, j1g, j2g, j3g;
  {
    int j = lane;
    float a = -3e38f;
    if (j < RR) {
      a = 0.f;
      const float* qdp = qd + (size_t)(n * RR + r) * 64;   // wave-uniform broadcast row
      const float* kdp = kd + (size_t)(n * RR + j) * 64;   // per-lane contiguous row
      #pragma unroll 16
      for (int c = 0; c < 64; c++)
        a += qdp[c] * kdp[c];
    }
    int jj4[4];
    #pragma unroll
    for (int t = 0; t < 4; t++) {
      float bv = a; int bj = j;
      #pragma unroll
      for (int d = 32; d >= 1; d >>= 1) {
        float ov = __shfl_xor(bv, d, 64);
        int oj = __shfl_xor(bj, d, 64);
        if (ov > bv || (ov == bv && oj < bj)) { bv = ov; bj = oj; }
      }
      jj4[t] = bj;
      if (j == bj) a = -3e38f;
    }
    j0g = jj4[0]; j1g = jj4[1]; j2g = jj4[2]; j3g = jj4[3];
  }
  int m0 = qsp * 128 + wv * 16;
  const bf16* qbase = qR + ((size_t)(n * RR + r)) * RS * 64;
  bf16x8 qF[2];
  #pragma unroll
  for (int kk = 0; kk < 2; kk++)
    qF[kk] = *(const bf16x8*)(qbase + (m0 + lo) * 64 + kk * 32 + hi * 8);

  int gofsK, gofsV;
  {
    int rowT = wv * 8 + (lane >> 3);
    int c4 = ((lane & 7) ^ rowT) & 7;
    gofsK = rowT * 128 + c4 * 16;
    gofsV = rowT * 512 + c4 * 16;
  }

  f32x4 zero4 = {0.f, 0.f, 0.f, 0.f};
  f32x4 Oacc[4];
  #pragma unroll
  for (int di = 0; di < 4; di++) Oacc[di] = zero4;
  float mrun = -3e38f, lrun = 0.f;   // lrun is PER-LANE PARTIAL (own 16 k-slots); reduced once at end

  #define ISSUE_TILE(JREG, SUB, BUF) do {                                            \
    const char* kb_ = (const char*)(kR + ((size_t)(n * RR + (JREG))) * RS * 64) + (SUB) * 8192; \
    const char* vb_ = (const char*)(vT + ((size_t)(n * RR + (JREG))) * 64 * RS) + (SUB) * 128;  \
    gl_lds16(kb_ + gofsK, (char*)sKd + (BUF) * 8192 + wv * 1024);                    \
    gl_lds16(vb_ + gofsV, (char*)sVd + (BUF) * 8192 + wv * 1024);                    \
    if (wv == 0) gl_lds4(maskr + ((size_t)(n * RR + (JREG))) * RS + (SUB) * 64 + lane, (char*)sMaskB[(BUF)]); \
  } while (0)

  ISSUE_TILE(j0g, 0, 0);

  for (int ts = 0; ts < 16; ts++) {
    int cur = ts & 1;
    asm volatile("s_waitcnt lgkmcnt(0)" ::: "memory");
    __builtin_amdgcn_s_barrier();
    __builtin_amdgcn_sched_barrier(0);
    if (ts < 15) {
      int nts = ts + 1;
      int jn = (nts < 8) ? (nts < 4 ? j0g : j1g) : (nts < 12 ? j2g : j3g);
      int nsub = nts & 3;
      ISSUE_TILE(jn, nsub, cur ^ 1);
      if (wv == 0) { asm volatile("s_waitcnt vmcnt(3)" ::: "memory"); }
      else         { asm volatile("s_waitcnt vmcnt(2)" ::: "memory"); }
    } else {
      asm volatile("s_waitcnt vmcnt(0)" ::: "memory");
    }
    __builtin_amdgcn_s_barrier();
    __builtin_amdgcn_sched_barrier(0);
    const char* sK = (const char*)sKd + cur * 8192;
    const char* sV = (const char*)sVd + cur * 8192;
    f32x4 Sacc[4];
    #pragma unroll
    for (int ni = 0; ni < 4; ni++) Sacc[ni] = zero4;
    #pragma unroll
    for (int kk = 0; kk < 2; kk++) {
      #pragma unroll
      for (int ni = 0; ni < 4; ni++) {
        bf16x8 kF = *(const bf16x8*)(sK + swz128(ni * 16 + lo, kk * 32 + hi * 8));
        Sacc[ni] = __builtin_amdgcn_mfma_f32_16x16x32_bf16(kF, qF[kk], Sacc[ni], 0, 0, 0);
      }
    }
    const float* mB = sMaskB[cur];
    float ml = -3e38f;
    #pragma unroll
    for (int ni = 0; ni < 4; ni++) {
      #pragma unroll
      for (int jj = 0; jj < 4; jj++) {
        float sv = Sacc[ni][jj] + mB[ni * 16 + hi * 4 + jj];
        Sacc[ni][jj] = sv;
        ml = fmaxf(ml, sv);
      }
    }
    ml = fmaxf(ml, __shfl_xor(ml, 16, 64));
    ml = fmaxf(ml, __shfl_xor(ml, 32, 64));
    // ---- defer-max (T13): skip rescale when max growth <= 8 (wave-uniform decision) ----
    bool skip = __all(ml <= mrun + 8.f);
    float nm, sc;
    if (skip) { nm = mrun; sc = 1.f; }
    else      { nm = fmaxf(mrun, ml); sc = __expf(mrun - nm); }
    float rs = 0.f;   // per-lane partial sum over this lane's 16 k-slots
    bf16* sPw = sP[wv];
    #pragma unroll
    for (int ni = 0; ni < 4; ni++) {
      bf16x4 p4;
      #pragma unroll
      for (int jj = 0; jj < 4; jj++) {
        float pv = __expf(Sacc[ni][jj] - nm);
        rs += pv;
        p4[jj] = (bf16)pv;
      }
      *(bf16x4*)((char*)sPw + swz128(lo, ni * 16 + hi * 4)) = p4;
    }
    // deferred l-sum: keep lrun per-lane; cross-lane reduce happens ONCE in epilogue
    mrun = nm;
    if (skip) {
      lrun += rs;
    } else {
      lrun = lrun * sc + rs;
      float scq[4];
      #pragma unroll
      for (int jj = 0; jj < 4; jj++) scq[jj] = __shfl(sc, hi * 4 + jj, 16);
      #pragma unroll
      for (int di = 0; di < 4; di++)
        #pragma unroll
        for (int jj = 0; jj < 4; jj++) Oacc[di][jj] *= scq[jj];
    }
    #pragma unroll
    for (int kk = 0; kk < 2; kk++) {
      bf16x8 pF = *(const bf16x8*)((const char*)sPw + swz128(lo, kk * 32 + hi * 8));
      #pragma unroll
      for (int di = 0; di < 4; di++) {
        bf16x8 vF = *(const bf16x8*)(sV + swz128(di * 16 + lo, kk * 32 + hi * 8));
        Oacc[di] = __builtin_amdgcn_mfma_f32_16x16x32_bf16(pF, vF, Oacc[di], 0, 0, 0);
      }
    }
  }
  #undef ISSUE_TILE
  __syncthreads();
  // final cross-lane l reduction (4 hi-lanes of each q-row share identical sc history)
  float lsum = lrun;
  lsum += __shfl_xor(lsum, 16, 64);
  lsum += __shfl_xor(lsum, 32, 64);
  float inv = 1.f / lsum;
  float invq[4];
  #pragma unroll
  for (int jj = 0; jj < 4; jj++) invq[jj] = __shfl(inv, hi * 4 + jj, 16);
  bf16* sOut = (bf16*)sKd;
  #pragma unroll
  for (int jj = 0; jj < 4; jj++) {
    int row = wv * 16 + hi * 4 + jj;
    #pragma unroll
    for (int di = 0; di < 4; di++)
      sOut[row * 64 + di * 16 + lo] = (bf16)(Oacc[di][jj] * invq[jj]);
  }
  __syncthreads();
  bf16* dst = attnRb + (((size_t)(n * RR + r)) * RS + qsp * 128) * 64;
  #pragma unroll
  for (int it = 0; it < 2; it++) {
    int idx = tid + it * 512;
    *(uint4*)(dst + idx * 8) = *(const uint4*)(sOut + idx * 8);
  }
}

// ---------------- fused lepe + proj (8 waves): dw5x5 + from_regions + proj GEMM + residual ----------------
__global__ __launch_bounds__(512) void k_lepe3(const bf16* __restrict__ v_t, const bf16* __restrict__ attnRb,
    const float* __restrict__ lw, const float* __restrict__ lb,
    const bf16* __restrict__ pwb, const float* __restrict__ pb, float* __restrict__ xo) {
  __shared__ __align__(16) char smem[64000];
  bf16* sH = (bf16*)smem;               // 400*72 bf16 = 57600B (halo)
  float* sW = (float*)(smem + 57600);   // 25*64 f32 = 6400B
  bf16* zA = (bf16*)smem;               // overlay: 256x64 A-tile (32768B)
  bf16* sBp = (bf16*)(smem + 32768);    // overlay: 64x64 proj weights (8192B)
  int r = blockIdx.x, n = blockIdx.y;
  int rh = (r / 7) * 16, rw = (r % 7) * 16;
  int tid = threadIdx.x, lane = tid & 63, wv = tid >> 6;
  int lo = lane & 15, hi = lane >> 4;
  for (int i = tid; i < 1600; i += 512) { int c = i / 25, k = i % 25; sW[k * 64 + c] = lw[c * 25 + k]; }
  for (int g = tid; g < 3200; g += 512) {
    int pix = g >> 3, c4 = g & 7;
    int yy = pix / 20, xx = pix % 20;
    int hh = rh + yy - 2, ww = rw + xx - 2;
    uint4 d = {0, 0, 0, 0};
    if ((unsigned)hh < HW && (unsigned)ww < HW)
      d = *(const uint4*)(v_t + ((size_t)n * PP + hh * HW + ww) * 64 + c4 * 8);
    *(uint4*)((char*)sH + pix * 144 + c4 * 16) = d;
  }
  __syncthreads();
  int pixel = tid >> 1, part = tid & 1;
  int y = pixel >> 4, x = pixel & 15;
  float acc[32];
  const bf16* ar = attnRb + (((size_t)(n * RR + r)) * RS + pixel) * 64 + part * 32;
  #pragma unroll
  for (int c8 = 0; c8 < 4; c8++) {
    bf16x8 av = *(const bf16x8*)(ar + c8 * 8);
    #pragma unroll
    for (int j = 0; j < 8; j++) acc[c8 * 8 + j] = lb[part * 32 + c8 * 8 + j] + (float)av[j];
  }
  for (int t25 = 0; t25 < 25; t25++) {
    int dh = t25 / 5, dw = t25 % 5;
    int pix = (y + dh) * 20 + (x + dw);
    #pragma unroll
    for (int c8 = 0; c8 < 4; c8++) {
      bf16x8 hv = *(const bf16x8*)((const char*)sH + pix * 144 + (part * 4 + c8) * 16);
      #pragma unroll
      for (int j = 0; j < 8; j++) acc[c8 * 8 + j] += (float)hv[j] * sW[t25 * 64 + part * 32 + c8 * 8 + j];
    }
  }
  __syncthreads();   // halo reads done -> safe to overlay zA/sBp
  #pragma unroll
  for (int i = 0; i < 4; i++) {
    bf16x8 o8;
    #pragma unroll
    for (int j = 0; j < 8; j++) o8[j] = (bf16)acc[i * 8 + j];
    *(bf16x8*)((char*)zA + swz128(pixel, part * 32 + i * 8)) = o8;
  }
  { // proj weight staging: 512 uint4 one pass
    int oo = tid >> 3, q8 = tid & 7;
    uint4 d = *(const uint4*)(pwb + (size_t)oo * 64 + q8 * 8);
    *(uint4*)((char*)sBp + swz128(oo, q8 * 8)) = d;
  }
  __syncthreads();
  f32x4 acc2[2][4];
  #pragma unroll
  for (int mi = 0; mi < 2; mi++)
    #pragma unroll
    for (int ni = 0; ni < 4; ni++) acc2[mi][ni] = (f32x4){0.f, 0.f, 0.f, 0.f};
  #pragma unroll
  for (int kk = 0; kk < 2; kk++) {
    bf16x8 aF[2], bF[4];
    #pragma unroll
    for (int mi = 0; mi < 2; mi++)
      aF[mi] = *(const bf16x8*)((const char*)zA + swz128(wv * 32 + mi * 16 + lo, kk * 32 + hi * 8));
    #pragma unroll
    for (int ni = 0; ni < 4; ni++)
      bF[ni] = *(const bf16x8*)((const char*)sBp + swz128(ni * 16 + lo, kk * 32 + hi * 8));
    #pragma unroll
    for (int mi = 0; mi < 2; mi++)
      #pragma unroll
      for (int ni = 0; ni < 4; ni++)
        acc2[mi][ni] = __builtin_amdgcn_mfma_f32_16x16x32_bf16(aF[mi], bF[ni], acc2[mi][ni], 0, 0, 0);
  }
  #pragma unroll
  for (int ni = 0; ni < 4; ni++) {
    float bv = pb[ni * 16 + lo];
    #pragma unroll
    for (int mi = 0; mi < 2; mi++) {
      #pragma unroll
      for (int r2 = 0; r2 < 4; r2++) {
        int s = wv * 32 + mi * 16 + hi * 4 + r2;
        int p = (rh + (s >> 4)) * HW + rw + (s & 15);
        xo[((size_t)n * PP + p) * 64 + ni * 16 + lo] += acc2[mi][ni][r2] + bv;
      }
    }
  }
}

// ---------------- fused MLP (8 waves, 128 rows): LN2 + fc1 + gelu + fc2 + residual ----------------
__global__ __launch_bounds__(512) void k_mlp(const float* __restrict__ xin, const float* __restrict__ lng,
    const float* __restrict__ lnb, const bf16* __restrict__ w1b, const float* __restrict__ b1,
    const bf16* __restrict__ w2b, const float* __restrict__ b2, float* __restrict__ xo) {
  __shared__ bf16 sA[128 * 64];     // 16KB
  __shared__ bf16 sW[128 * 64];     // 16KB shared: W1-half (128x64) / W2-half (64x128)
  __shared__ bf16 sHh[128 * 128];   // 32KB
  int n = blockIdx.y;
  int p0 = blockIdx.x * 128;
  int tid = threadIdx.x, lane = tid & 63, wv = tid >> 6;
  int lo = lane & 15, hi = lane >> 4;
  { // fused LN staging: 4 threads per row (128 rows), 16 channels each
    int row = tid >> 2, part = tid & 3;
    const float* xp = xin + ((size_t)n * PP + p0 + row) * 64 + part * 16;
    float v[16]; float s = 0.f, sq = 0.f;
    #pragma unroll
    for (int i = 0; i < 4; i++) {
      float4 d = *(const float4*)&xp[i * 4];
      v[i*4]=d.x; v[i*4+1]=d.y; v[i*4+2]=d.z; v[i*4+3]=d.w;
      s += d.x+d.y+d.z+d.w;
      sq += d.x*d.x+d.y*d.y+d.z*d.z+d.w*d.w;
    }
    s += __shfl_xor(s, 1, 64); sq += __shfl_xor(sq, 1, 64);
    s += __shfl_xor(s, 2, 64); sq += __shfl_xor(sq, 2, 64);
    float mu = s * (1.f/64.f);
    float rstd = rsqrtf(fmaxf(sq * (1.f/64.f) - mu*mu, 0.f) + 1e-5f);
    #pragma unroll
    for (int j2 = 0; j2 < 2; j2++) {
      bf16x8 o8;
      #pragma unroll
      for (int e = 0; e < 8; e++) {
        int c = part*16 + j2*8 + e;
        o8[e] = (bf16)((v[j2*8+e] - mu) * rstd * lng[c] + lnb[c]);
      }
      *(bf16x8*)((char*)sA + swz128(row, part*16 + j2*8)) = o8;
    }
  }
  f32x4 oacc[4];
  #pragma unroll
  for (int ni = 0; ni < 4; ni++) oacc[ni] = (f32x4){0.f, 0.f, 0.f, 0.f};
  for (int half = 0; half < 2; half++) {
    // stage W1 half: 128x64 bf16 = 1024 uint4, 2/thread
    #pragma unroll
    for (int it = 0; it < 2; it++) {
      int idx = tid + it * 512;
      int oo = idx >> 3, q8 = idx & 7;
      uint4 d = *(const uint4*)(w1b + (size_t)(half * 128 + oo) * 64 + q8 * 8);
      *(uint4*)((char*)sW + swz128(oo, q8 * 8)) = d;
    }
    __syncthreads();
    f32x4 hacc[8];
    #pragma unroll
    for (int ni = 0; ni < 8; ni++) hacc[ni] = (f32x4){0.f, 0.f, 0.f, 0.f};
    #pragma unroll
    for (int kk = 0; kk < 2; kk++) {
      bf16x8 aF = *(const bf16x8*)((const char*)sA + swz128(wv * 16 + lo, kk * 32 + hi * 8));
      #pragma unroll
      for (int ni = 0; ni < 8; ni++) {
        bf16x8 bF = *(const bf16x8*)((const char*)sW + swz128(ni * 16 + lo, kk * 32 + hi * 8));
        hacc[ni] = __builtin_amdgcn_mfma_f32_16x16x32_bf16(aF, bF, hacc[ni], 0, 0, 0);
      }
    }
    #pragma unroll
    for (int ni = 0; ni < 8; ni++) {
      float bv = b1[half * 128 + ni * 16 + lo];
      #pragma unroll
      for (int r2 = 0; r2 < 4; r2++) {
        float hval = gelu_fast(hacc[ni][r2] + bv);
        *(bf16*)((char*)sHh + swzg(wv * 16 + hi * 4 + r2, ni * 16 + lo, 256)) = (bf16)hval;
      }
    }
    __syncthreads();   // fc1 reads of sW done -> safe to overwrite with W2
    // stage W2 half: 64 rows x 128 cols bf16 = 1024 uint4, 2/thread
    #pragma unroll
    for (int it = 0; it < 2; it++) {
      int idx = tid + it * 512;
      int oo = idx >> 4, q8 = idx & 15;
      uint4 d = *(const uint4*)(w2b + (size_t)oo * 256 + half * 128 + q8 * 8);
      *(uint4*)((char*)sW + swzg(oo, q8 * 8, 256)) = d;
    }
    __syncthreads();
    #pragma unroll
    for (int kk = 0; kk < 4; kk++) {
      bf16x8 aH = *(const bf16x8*)((const char*)sHh + swzg(wv * 16 + lo, kk * 32 + hi * 8, 256));
      #pragma unroll
      for (int ni = 0; ni < 4; ni++) {
        bf16x8 bF = *(const bf16x8*)((const char*)sW + swzg(ni * 16 + lo, kk * 32 + hi * 8, 256));
        oacc[ni] = __builtin_amdgcn_mfma_f32_16x16x32_bf16(aH, bF, oacc[ni], 0, 0, 0);
      }
    }
    __syncthreads();   // fc2 reads done -> next half may overwrite sW/sHh
  }
  #pragma unroll
  for (int ni = 0; ni < 4; ni++) {
    float bv = b2[ni * 16 + lo];
    #pragma unroll
    for (int r2 = 0; r2 < 4; r2++) {
      int p = p0 + wv * 16 + hi * 4 + r2;
      xo[((size_t)n * PP + p) * 64 + ni * 16 + lo] += oacc[ni][r2] + bv;
    }
  }
}

// ---------------- final untranspose: x_t[p][c] -> out[c][p] ----------------
__global__ __launch_bounds__(256) void k_untr(const float* __restrict__ x_t, float* __restrict__ out) {
  __shared__ float tile[64][68];
  int n = blockIdx.y; int p0 = blockIdx.x * 64;
  int tid = threadIdx.x;
  #pragma unroll
  for (int it = 0; it < 4; it++) {
    int g = tid + it * 256;
    int row = g >> 4, q = g & 15;
    float4 d = *(const float4*)&x_t[((size_t)n * PP + p0 + row) * 64 + q * 4];
    *(float4*)&tile[row][q * 4] = d;
  }
  __syncthreads();
  #pragma unroll
  for (int it = 0; it < 4; it++) {
    int g = tid + it * 256;
    int c = g >> 4, q = g & 15;
    float4 v;
    v.x = tile[q * 4 + 0][c]; v.y = tile[q * 4 + 1][c];
    v.z = tile[q * 4 + 2][c]; v.w = tile[q * 4 + 3][c];
    *(float4*)&out[((size_t)(n * 64 + c)) * PP + p0 + q * 4] = v;
  }
}

extern "C" void kernel_launch(void* const* d_in, const int* in_sizes, int n_in,
                              void* d_out, int out_size, void* d_ws, size_t ws_size,
                              hipStream_t stream) {
  const float* ex0 = (const float*)d_in[0];
  const float* ex  = (const float*)d_in[1];
  const float* img = (const float*)d_in[2];
  const float* pre = (const float*)d_in[3];
  const float* c0w = (const float*)d_in[4];
  const float* c0b = (const float*)d_in[5];
  const float* ln1g = (const float*)d_in[6];
  const float* ln1b = (const float*)d_in[7];
  const float* ln2g = (const float*)d_in[8];
  const float* ln2b = (const float*)d_in[9];
  const float* qkvw = (const float*)d_in[10];
  const float* qkvb = (const float*)d_in[11];
  const float* lw = (const float*)d_in[12];
  const float* lb = (const float*)d_in[13];
  const float* pw = (const float*)d_in[14];
  const float* pb = (const float*)d_in[15];
  const float* f1w = (const float*)d_in[16];
  const float* f1b = (const float*)d_in[17];
  const float* f2w = (const float*)d_in[18];
  const float* f2b = (const float*)d_in[19];

  float* W = (float*)d_ws;
  size_t o = 0;
  bf16* xct = (bf16*)(W + o);  o += (size_t)BB * GP * CK / 2;
  float* x_t  = W + o;         o += 3211264;
  bf16* attnRb = (bf16*)(W + o); o += 1605632;
  bf16* v_t  = (bf16*)(W + o); o += 1605632;
  bf16* qR   = (bf16*)(W + o); o += 1605632;
  bf16* kR   = (bf16*)(W + o); o += 1605632;
  bf16* vT   = (bf16*)(W + o); o += 1605632;
  float* qd = W + o;           o += 12544;
  float* kd = W + o;           o += 12544;
  float* maskr = W + o;        o += 50176;
  bf16* wTb = (bf16*)(W + o);  o += 46080;
  bf16* qkvwb = (bf16*)(W + o); o += 24576;   // 4*192*64 bf16
  bf16* pwb   = (bf16*)(W + o); o += 8192;    // 4*64*64
  bf16* f1wb  = (bf16*)(W + o); o += 32768;   // 4*256*64
  bf16* f2wb  = (bf16*)(W + o); o += 32768;   // 4*64*256

  // merged setup: 142 ring blocks + 360 wt2 blocks + 768 wcvt blocks = 1270
  k_setup<<<dim3(1270), dim3(256), 0, stream>>>(xct, c0w, wTb,
      qkvw, qkvwb, pw, pwb, f1w, f1wb, f2w, f2wb);
  k_prep2<<<dim3(196, BB), dim3(256), 0, stream>>>(ex0, ex, img, pre, xct, maskr);
  k_conv0m<<<dim3(98, BB), dim3(256), 0, stream>>>(xct, wTb, c0b, x_t);
  for (int i = 0; i < 4; i++) {
    k_qkvr<<<dim3(RR, BB), dim3(512), 0, stream>>>(x_t, ln1g + i * 64, ln1b + i * 64,
        qkvwb + (size_t)i * 192 * 64, qkvb + i * 192, qR, kR, v_t, vT, qd, kd);
    k_attn<<<dim3(BB * RR * 2), dim3(512), 0, stream>>>(qR, kR, vT, maskr, qd, kd, attnRb);
    k_lepe3<<<dim3(RR, BB), dim3(512), 0, stream>>>(v_t, attnRb, lw + (size_t)i * 64 * 25, lb + i * 64,
        pwb + (size_t)i * 64 * 64, pb + i * 64, x_t);
    k_mlp<<<dim3(98, BB), dim3(512), 0, stream>>>(x_t, ln2g + i * 64, ln2b + i * 64,
        f1wb + (size_t)i * 256 * 64, f1b + i * 256, f2wb + (size_t)i * 64 * 256, f2b + i * 64, x_t);
  }
  k_untr<<<dim3(196, BB), dim3(256), 0, stream>>>(x_t, (float*)d_out);
}

// Round 24
// 440.887 us; speedup vs baseline: 1.0225x; 1.0225x over previous
//
#include <hip/hip_runtime.h>

#define HW 112
#define PP 12544
#define BB 4
#define RR 49
#define RS 256
#define GW 114          // padded grid width (zero ring)
#define GP (GW*GW)      // 12996
#define CK 160          // padded channels for conv0

typedef __bf16 bf16;
typedef __bf16 bf16x8 __attribute__((ext_vector_type(8)));
typedef __bf16 bf16x4 __attribute__((ext_vector_type(4)));
typedef float f32x4 __attribute__((ext_vector_type(4)));

// XOR-swizzled byte offset in a row-major bf16 tile; rowbytes ∈ {128,256,512}
__device__ __forceinline__ int swzg(int row, int halfcol, int rowbytes) {
  int byte = halfcol * 2;
  return row * rowbytes + (byte & ~127) + ((((byte >> 4) ^ row) & 7) * 16) + (byte & 15);
}
__device__ __forceinline__ int swz128(int row, int halfcol) { return swzg(row, halfcol, 128); }

// tanh-approx gelu (max abs err ~3e-4 vs exact erf form)
__device__ __forceinline__ float gelu_fast(float x) {
  float y = 0.7978845608f * (x + 0.044715f * x * x * x);
  float t = __expf(-2.f * fabsf(y));
  float th = (1.f - t) / (1.f + t);
  th = copysignf(th, y);
  return 0.5f * x * (1.f + th);
}

// async global->LDS (no VGPR round-trip). LDS dest = wave-uniform base + lane*size.
__device__ __forceinline__ void gl_lds16(const void* g, void* l) {
  __builtin_amdgcn_global_load_lds((const __attribute__((address_space(1))) unsigned int*)g,
                                   (__attribute__((address_space(3))) unsigned int*)l, 16, 0, 0);
}
__device__ __forceinline__ void gl_lds4(const void* g, void* l) {
  __builtin_amdgcn_global_load_lds((const __attribute__((address_space(1))) unsigned int*)g,
                                   (__attribute__((address_space(3))) unsigned int*)l, 4, 0, 0);
}

// ---------------- zero only the 1-pixel ring of xct ----------------
__global__ __launch_bounds__(256) void k_ring(bf16* __restrict__ xct) {
  int t = blockIdx.x * 256 + threadIdx.x;   // 4 * 452 * 20 = 36160 uint4s
  if (t >= BB * 452 * 20) return;
  int c4 = t % 20; int rem = t / 20; int ri = rem % 452; int n = rem / 452;
  int hh, ww;
  if (ri < 114)      { hh = 0;   ww = ri; }
  else if (ri < 228) { hh = 113; ww = ri - 114; }
  else if (ri < 340) { hh = 1 + (ri - 228); ww = 0; }
  else               { hh = 1 + (ri - 340); ww = 113; }
  uint4 zz = {0, 0, 0, 0};
  *(uint4*)(xct + ((size_t)n * GP + hh * GW + ww) * CK + c4 * 8) = zz;
}

// ---------------- prep: downsample+concat -> xcat_t bf16 [n][grid 114x114][160], mask ----------------
__global__ __launch_bounds__(256) void k_prep2(const float* __restrict__ ex0, const float* __restrict__ ex,
    const float* __restrict__ img, const float* __restrict__ pre,
    bf16* __restrict__ xct, float* __restrict__ maskr) {
  __shared__ bf16 sT2[64 * 168];
  int n = blockIdx.y;
  int p0 = blockIdx.x * 64;
  int tid = threadIdx.x;
  uint4 zz = {0, 0, 0, 0};
  for (int i2 = tid; i2 < 1344; i2 += 256) ((uint4*)sT2)[i2] = zz;
  __syncthreads();
  int l = tid & 63, g = tid >> 6;
  int p = p0 + l;
  int h = p / HW, w = p % HW;
  for (int c = g; c < 131; c += 4) {
    float val;
    if (c < 64) {
      const float* s = ex0 + (((size_t)(n * 64 + c)) * 224 + 2 * h) * 224 + 2 * w;
      val = 0.5f * (0.5f * (s[0] + s[224]) + 0.5f * (s[1] + s[225]));
    } else if (c < 128) {
      val = ex[((size_t)(n * 64 + (c - 64))) * PP + p];
    } else {
      const float* s = img + (((size_t)(n * 3 + (c - 128))) * 224 + 2 * h) * 224 + 2 * w;
      val = 0.5f * (0.5f * (s[0] + s[224]) + 0.5f * (s[1] + s[225]));
    }
    sT2[l * 168 + c] = (bf16)val;
  }
  if (tid < 64) {
    const float* s = pre + ((size_t)n * 224 + 2 * h) * 224 + 2 * w;
    float v = 0.5f * (0.5f * (s[0] + s[224]) + 0.5f * (s[1] + s[225]));
    int r = (h >> 4) * 7 + (w >> 4); int sIdx = (h & 15) * 16 + (w & 15);
    maskr[(n * RR + r) * RS + sIdx] = (v > 0.0f) ? 0.0f : -100.0f;
  }
  __syncthreads();
  for (int i2 = tid; i2 < 1280; i2 += 256) {
    int row = i2 / 20, ch = i2 % 20;
    int pr = p0 + row;
    int hh = pr / HW, ww = pr % HW;
    uint4 d = *(const uint4*)(sT2 + row * 168 + ch * 8);
    *(uint4*)(xct + ((size_t)n * GP + (hh + 1) * GW + ww + 1) * CK + ch * 8) = d;
  }
}

// ---------------- conv0 weights -> wTb bf16 [9tap][5ks][64o][32c] ----------------
__global__ __launch_bounds__(256) void k_wt2(const float* __restrict__ w, bf16* __restrict__ wTb) {
  int t = blockIdx.x * 256 + threadIdx.x;
  if (t >= 9 * 5 * 64 * 32) return;
  int cc = t & 31; int o = (t >> 5) & 63; int ks = (t >> 11) % 5; int k = t / 10240;
  int c = ks * 32 + cc;
  wTb[t] = (bf16)((c < 131) ? w[((size_t)(o * 131) + c) * 9 + k] : 0.f);
}

// ---------------- bulk f32->bf16 weight conversion (qkv, proj, fc1, fc2) ----------------
__global__ __launch_bounds__(256) void k_wcvt(const float* __restrict__ s0, bf16* __restrict__ d0, int n0,
    const float* __restrict__ s1, bf16* __restrict__ d1, int n1,
    const float* __restrict__ s2, bf16* __restrict__ d2, int n2,
    const float* __restrict__ s3, bf16* __restrict__ d3, int n3) {
  int t = blockIdx.x * 256 + threadIdx.x;
  if (t < n0) { d0[t] = (bf16)s0[t]; return; }
  t -= n0;
  if (t < n1) { d1[t] = (bf16)s1[t]; return; }
  t -= n1;
  if (t < n2) { d2[t] = (bf16)s2[t]; return; }
  t -= n2;
  if (t < n3) { d3[t] = (bf16)s3[t]; }
}

// ---------------- conv0 as MFMA implicit GEMM ----------------
__global__ __launch_bounds__(256) void k_conv0m(const bf16* __restrict__ xct, const bf16* __restrict__ wTb,
    const float* __restrict__ bias, float* __restrict__ out_t) {
  __shared__ bf16 sA[128 * 32];
  __shared__ bf16 sB[64 * 32];
  int n = blockIdx.y;
  int p0 = blockIdx.x * 128;
  int tid = threadIdx.x, lane = tid & 63, wv = tid >> 6;
  int lo = lane & 15, hi = lane >> 4;
  size_t gofsA[2];
  #pragma unroll
  for (int it = 0; it < 2; it++) {
    int idx = tid + it * 256;
    int row = idx >> 2, ch = idx & 3;
    int p = p0 + row;
    int hh = p / HW, ww = p % HW;
    gofsA[it] = ((size_t)(hh + 1) * GW + ww + 1) * (CK * 2) + ch * 16;
  }
  const char* xbase = (const char*)(xct + (size_t)n * GP * CK);
  f32x4 acc[2][4];
  #pragma unroll
  for (int mi = 0; mi < 2; mi++)
    #pragma unroll
    for (int ni = 0; ni < 4; ni++) acc[mi][ni] = (f32x4){0.f, 0.f, 0.f, 0.f};
  for (int tap = 0; tap < 9; tap++) {
    long shift = (long)((tap / 3 - 1) * GW + (tap % 3 - 1)) * (CK * 2);
    for (int ks = 0; ks < 5; ks++) {
      uint4 a0 = *(const uint4*)(xbase + gofsA[0] + shift + ks * 64);
      uint4 a1 = *(const uint4*)(xbase + gofsA[1] + shift + ks * 64);
      uint4 b0 = *(const uint4*)((const char*)wTb + ((size_t)(tap * 5 + ks) * 2048 + tid * 8) * 2);
      __syncthreads();
      *(uint4*)((char*)sA + tid * 16) = a0;
      *(uint4*)((char*)sA + (tid + 256) * 16) = a1;
      *(uint4*)((char*)sB + tid * 16) = b0;
      __syncthreads();
      bf16x8 aF[2], bF[4];
      #pragma unroll
      for (int mi = 0; mi < 2; mi++)
        aF[mi] = *(const bf16x8*)((const char*)sA + (wv * 32 + mi * 16 + lo) * 64 + hi * 16);
      #pragma unroll
      for (int ni = 0; ni < 4; ni++)
        bF[ni] = *(const bf16x8*)((const char*)sB + (ni * 16 + lo) * 64 + hi * 16);
      #pragma unroll
      for (int mi = 0; mi < 2; mi++)
        #pragma unroll
        for (int ni = 0; ni < 4; ni++)
          acc[mi][ni] = __builtin_amdgcn_mfma_f32_16x16x32_bf16(aF[mi], bF[ni], acc[mi][ni], 0, 0, 0);
    }
  }
  #pragma unroll
  for (int ni = 0; ni < 4; ni++) {
    float bv = bias[ni * 16 + lo];
    #pragma unroll
    for (int mi = 0; mi < 2; mi++) {
      #pragma unroll
      for (int r2 = 0; r2 < 4; r2++) {
        int p = p0 + wv * 32 + mi * 16 + hi * 4 + r2;
        out_t[((size_t)n * PP + p) * 64 + ni * 16 + lo] = acc[mi][ni][r2] + bv;
      }
    }
  }
}

// ---------------- fused region qkv (8 waves): LN1 + single-stage weights + 3 barrier-free GEMMs ----------------
__global__ __launch_bounds__(512) void k_qkvr(const float* __restrict__ xin, const float* __restrict__ lng,
    const float* __restrict__ lnb, const bf16* __restrict__ wb, const float* __restrict__ bias,
    bf16* __restrict__ qRo, bf16* __restrict__ kRo, bf16* __restrict__ vto, bf16* __restrict__ vTo,
    float* __restrict__ qd, float* __restrict__ kd) {
  __shared__ __align__(16) char smem[61440];
  bf16* sA = (bf16*)smem;               // 256x64 tile, 32768B
  bf16* sB = (bf16*)(smem + 32768);     // 192x64 weights, 24576B
  float* rq = (float*)(smem + 57344);   // [8][64] 2048B
  float* rk = (float*)(smem + 59392);   // [8][64] 2048B
  bf16* sT = (bf16*)smem;               // overlay for vT transpose (64x264)
  int r = blockIdx.x, n = blockIdx.y;
  int nr = n * RR + r;
  int rh = (r / 7) * 16, rw = (r % 7) * 16;
  int tid = threadIdx.x, lane = tid & 63, wv = tid >> 6;
  int lo = lane & 15, hi = lane >> 4;
  { // LN staging: 2 threads per pixel-row, single pass
    int row = tid >> 1, part = tid & 1;
    int y = row >> 4, x = row & 15;
    const float* xp = xin + ((size_t)n * PP + (rh + y) * HW + rw + x) * 64 + part * 32;
    float v[32]; float s = 0.f, sq = 0.f;
    #pragma unroll
    for (int i = 0; i < 8; i++) {
      float4 d = *(const float4*)&xp[i * 4];
      v[i*4]=d.x; v[i*4+1]=d.y; v[i*4+2]=d.z; v[i*4+3]=d.w;
      s += d.x+d.y+d.z+d.w;
      sq += d.x*d.x+d.y*d.y+d.z*d.z+d.w*d.w;
    }
    s += __shfl_xor(s, 1, 64); sq += __shfl_xor(sq, 1, 64);
    float mu = s * (1.f/64.f);
    float rstd = rsqrtf(fmaxf(sq * (1.f/64.f) - mu*mu, 0.f) + 1e-5f);
    #pragma unroll
    for (int j2 = 0; j2 < 4; j2++) {
      bf16x8 o8;
      #pragma unroll
      for (int e = 0; e < 8; e++) {
        int c = part*32 + j2*8 + e;
        o8[e] = (bf16)((v[j2*8+e] - mu) * rstd * lng[c] + lnb[c]);
      }
      *(bf16x8*)((char*)sA + swz128(row, part*32 + j2*8)) = o8;
    }
  }
  { // stage ALL qkv weights: 1536 uint4 = 3/thread
    #pragma unroll
    for (int it = 0; it < 3; it++) {
      int idx = tid + it * 512;
      int oo = idx >> 3, q8 = idx & 7;
      uint4 d = *(const uint4*)(wb + (size_t)oo * 64 + q8 * 8);
      *(uint4*)((char*)sB + swz128(oo, q8 * 8)) = d;
    }
  }
  __syncthreads();
  // ---- ob0: q ----
  {
    f32x4 acc[2][4];
    #pragma unroll
    for (int mi = 0; mi < 2; mi++)
      #pragma unroll
      for (int ni = 0; ni < 4; ni++) acc[mi][ni] = (f32x4){0.f, 0.f, 0.f, 0.f};
    #pragma unroll
    for (int kk = 0; kk < 2; kk++) {
      bf16x8 aF[2], bF[4];
      #pragma unroll
      for (int mi = 0; mi < 2; mi++)
        aF[mi] = *(const bf16x8*)((const char*)sA + swz128(wv * 32 + mi * 16 + lo, kk * 32 + hi * 8));
      #pragma unroll
      for (int ni = 0; ni < 4; ni++)
        bF[ni] = *(const bf16x8*)((const char*)sB + swz128(ni * 16 + lo, kk * 32 + hi * 8));
      #pragma unroll
      for (int mi = 0; mi < 2; mi++)
        #pragma unroll
        for (int ni = 0; ni < 4; ni++)
          acc[mi][ni] = __builtin_amdgcn_mfma_f32_16x16x32_bf16(aF[mi], bF[ni], acc[mi][ni], 0, 0, 0);
    }
    float part_[4] = {0.f, 0.f, 0.f, 0.f};
    #pragma unroll
    for (int ni = 0; ni < 4; ni++) {
      float bv = bias[ni * 16 + lo];
      #pragma unroll
      for (int mi = 0; mi < 2; mi++) {
        #pragma unroll
        for (int r2 = 0; r2 < 4; r2++) {
          float rv = acc[mi][ni][r2] + bv;
          int s = wv * 32 + mi * 16 + hi * 4 + r2;
          qRo[((size_t)nr * RS + s) * 64 + ni * 16 + lo] = (bf16)(rv * 0.125f);
          part_[ni] += rv;
        }
      }
      part_[ni] += __shfl_xor(part_[ni], 16, 64);
      part_[ni] += __shfl_xor(part_[ni], 32, 64);
      if (hi == 0) rq[wv * 64 + ni * 16 + lo] = part_[ni];
    }
  }
  // ---- ob1: k ----
  {
    f32x4 acc[2][4];
    #pragma unroll
    for (int mi = 0; mi < 2; mi++)
      #pragma unroll
      for (int ni = 0; ni < 4; ni++) acc[mi][ni] = (f32x4){0.f, 0.f, 0.f, 0.f};
    #pragma unroll
    for (int kk = 0; kk < 2; kk++) {
      bf16x8 aF[2], bF[4];
      #pragma unroll
      for (int mi = 0; mi < 2; mi++)
        aF[mi] = *(const bf16x8*)((const char*)sA + swz128(wv * 32 + mi * 16 + lo, kk * 32 + hi * 8));
      #pragma unroll
      for (int ni = 0; ni < 4; ni++)
        bF[ni] = *(const bf16x8*)((const char*)sB + swz128(64 + ni * 16 + lo, kk * 32 + hi * 8));
      #pragma unroll
      for (int mi = 0; mi < 2; mi++)
        #pragma unroll
        for (int ni = 0; ni < 4; ni++)
          acc[mi][ni] = __builtin_amdgcn_mfma_f32_16x16x32_bf16(aF[mi], bF[ni], acc[mi][ni], 0, 0, 0);
    }
    float part_[4] = {0.f, 0.f, 0.f, 0.f};
    #pragma unroll
    for (int ni = 0; ni < 4; ni++) {
      float bv = bias[64 + ni * 16 + lo];
      #pragma unroll
      for (int mi = 0; mi < 2; mi++) {
        #pragma unroll
        for (int r2 = 0; r2 < 4; r2++) {
          float rv = acc[mi][ni][r2] + bv;
          int s = wv * 32 + mi * 16 + hi * 4 + r2;
          kRo[((size_t)nr * RS + s) * 64 + ni * 16 + lo] = (bf16)rv;
          part_[ni] += rv;
        }
      }
      part_[ni] += __shfl_xor(part_[ni], 16, 64);
      part_[ni] += __shfl_xor(part_[ni], 32, 64);
      if (hi == 0) rk[wv * 64 + ni * 16 + lo] = part_[ni];
    }
  }
  // ---- ob2: v ----
  {
    f32x4 acc[2][4];
    #pragma unroll
    for (int mi = 0; mi < 2; mi++)
      #pragma unroll
      for (int ni = 0; ni < 4; ni++) acc[mi][ni] = (f32x4){0.f, 0.f, 0.f, 0.f};
    #pragma unroll
    for (int kk = 0; kk < 2; kk++) {
      bf16x8 aF[2], bF[4];
      #pragma unroll
      for (int mi = 0; mi < 2; mi++)
        aF[mi] = *(const bf16x8*)((const char*)sA + swz128(wv * 32 + mi * 16 + lo, kk * 32 + hi * 8));
      #pragma unroll
      for (int ni = 0; ni < 4; ni++)
        bF[ni] = *(const bf16x8*)((const char*)sB + swz128(128 + ni * 16 + lo, kk * 32 + hi * 8));
      #pragma unroll
      for (int mi = 0; mi < 2; mi++)
        #pragma unroll
        for (int ni = 0; ni < 4; ni++)
          acc[mi][ni] = __builtin_amdgcn_mfma_f32_16x16x32_bf16(aF[mi], bF[ni], acc[mi][ni], 0, 0, 0);
    }
    float vreg[4][2][4];
    #pragma unroll
    for (int ni = 0; ni < 4; ni++) {
      float bv = bias[128 + ni * 16 + lo];
      int ch = ni * 16 + lo;
      #pragma unroll
      for (int mi = 0; mi < 2; mi++) {
        #pragma unroll
        for (int r2 = 0; r2 < 4; r2++) {
          float rv = acc[mi][ni][r2] + bv;
          vreg[ni][mi][r2] = rv;
          int s = wv * 32 + mi * 16 + hi * 4 + r2;
          vto[((size_t)n * PP + (rh + (s >> 4)) * HW + rw + (s & 15)) * 64 + ch] = (bf16)rv;
        }
      }
    }
    __syncthreads();   // all waves done reading sA/sB -> safe to overlay sT
    #pragma unroll
    for (int ni = 0; ni < 4; ni++) {
      int ch = ni * 16 + lo;
      #pragma unroll
      for (int mi = 0; mi < 2; mi++) {
        #pragma unroll
        for (int r2 = 0; r2 < 4; r2++) {
          int s = wv * 32 + mi * 16 + hi * 4 + r2;
          sT[ch * 264 + s] = (bf16)vreg[ni][mi][r2];
        }
      }
    }
    __syncthreads();
    #pragma unroll
    for (int it = 0; it < 4; it++) {
      int idx = tid + it * 512;
      int row = idx >> 5, ch8 = idx & 31;
      uint4 d = *(const uint4*)(sT + row * 264 + ch8 * 8);
      *(uint4*)(vTo + ((size_t)nr * 64 + row) * 256 + ch8 * 8) = d;
    }
    if (tid < 64) {
      int c = tid;
      float aq = 0.f, ak = 0.f;
      #pragma unroll
      for (int w8 = 0; w8 < 8; w8++) { aq += rq[w8 * 64 + c]; ak += rk[w8 * 64 + c]; }
      qd[(n * 64 + c) * RR + r] = aq * (1.f / 256.f);
      kd[(n * 64 + c) * RR + r] = ak * (1.f / 256.f);
    }
  }
}

// ---------------- top-4 routing: one wave per query region ----------------
__global__ __launch_bounds__(64) void k_topk(const float* __restrict__ qd, const float* __restrict__ kd,
    int* __restrict__ gidx) {
  int pq = blockIdx.x, n = blockIdx.y;
  int j = threadIdx.x;
  float a = -3e38f;
  if (j < RR) {
    a = 0.f;
    for (int c = 0; c < 64; c++)
      a += qd[(n * 64 + c) * RR + pq] * kd[(n * 64 + c) * RR + j];
  }
  for (int t = 0; t < 4; t++) {
    float bv = a; int bj = j;
    #pragma unroll
    for (int d = 32; d >= 1; d >>= 1) {
      float ov = __shfl_xor(bv, d, 64);
      int oj = __shfl_xor(bj, d, 64);
      if (ov > bv || (ov == bv && oj < bj)) { bv = ov; bj = oj; }
    }
    if (j == 0) gidx[(n * RR + pq) * 4 + t] = bj;
    if (j == bj) a = -3e38f;
  }
}

// ---------------- gathered-region flash attention: 8-wave, swapped QK^T, defer-max, deferred l-sum ----------------
__global__ __launch_bounds__(512, 6) void k_attn(const bf16* __restrict__ qR, const bf16* __restrict__ kR,
    const bf16* __restrict__ vT, const float* __restrict__ maskr, const int* __restrict__ gidx,
    bf16* __restrict__ attnRb) {
  __shared__ bf16 sKd[2][64 * 64];
  __shared__ bf16 sVd[2][64 * 64];
  __shared__ bf16 sP[8][16 * 64];
  __shared__ float sMaskB[2][64];
  int bid = blockIdx.x;
  int newid = (bid & 7) * 49 + (bid >> 3);   // 392 = 8*49: bijective XCD chunking
  int n = newid / (RR * 2); int rem = newid % (RR * 2); int r = rem >> 1, qsp = rem & 1;
  int tid = threadIdx.x, lane = tid & 63, wv = tid >> 6;
  int lo = lane & 15, hi = lane >> 4;
  int m0 = qsp * 128 + wv * 16;
  const bf16* qbase = qR + ((size_t)(n * RR + r)) * RS * 64;
  bf16x8 qF[2];
  #pragma unroll
  for (int kk = 0; kk < 2; kk++)
    qF[kk] = *(const bf16x8*)(qbase + (m0 + lo) * 64 + kk * 32 + hi * 8);

  int gofsK, gofsV;
  {
    int rowT = wv * 8 + (lane >> 3);
    int c4 = ((lane & 7) ^ rowT) & 7;
    gofsK = rowT * 128 + c4 * 16;
    gofsV = rowT * 512 + c4 * 16;
  }

  const int* gptr = gidx + (n * RR + r) * 4;
  int j0g = gptr[0], j1g = gptr[1], j2g = gptr[2], j3g = gptr[3];

  f32x4 zero4 = {0.f, 0.f, 0.f, 0.f};
  f32x4 Oacc[4];
  #pragma unroll
  for (int di = 0; di < 4; di++) Oacc[di] = zero4;
  float mrun = -3e38f, lrun = 0.f;   // lrun is PER-LANE PARTIAL (own 16 k-slots); reduced once at end

  #define ISSUE_TILE(JREG, SUB, BUF) do {                                            \
    const char* kb_ = (const char*)(kR + ((size_t)(n * RR + (JREG))) * RS * 64) + (SUB) * 8192; \
    const char* vb_ = (const char*)(vT + ((size_t)(n * RR + (JREG))) * 64 * RS) + (SUB) * 128;  \
    gl_lds16(kb_ + gofsK, (char*)sKd + (BUF) * 8192 + wv * 1024);                    \
    gl_lds16(vb_ + gofsV, (char*)sVd + (BUF) * 8192 + wv * 1024);                    \
    if (wv == 0) gl_lds4(maskr + ((size_t)(n * RR + (JREG))) * RS + (SUB) * 64 + lane, (char*)sMaskB[(BUF)]); \
  } while (0)

  ISSUE_TILE(j0g, 0, 0);

  for (int ts = 0; ts < 16; ts++) {
    int cur = ts & 1;
    asm volatile("s_waitcnt lgkmcnt(0)" ::: "memory");
    __builtin_amdgcn_s_barrier();
    __builtin_amdgcn_sched_barrier(0);
    if (ts < 15) {
      int nts = ts + 1;
      int jn = (nts < 8) ? (nts < 4 ? j0g : j1g) : (nts < 12 ? j2g : j3g);
      int nsub = nts & 3;
      ISSUE_TILE(jn, nsub, cur ^ 1);
      if (wv == 0) { asm volatile("s_waitcnt vmcnt(3)" ::: "memory"); }
      else         { asm volatile("s_waitcnt vmcnt(2)" ::: "memory"); }
    } else {
      asm volatile("s_waitcnt vmcnt(0)" ::: "memory");
    }
    __builtin_amdgcn_s_barrier();
    __builtin_amdgcn_sched_barrier(0);
    const char* sK = (const char*)sKd + cur * 8192;
    const char* sV = (const char*)sVd + cur * 8192;
    f32x4 Sacc[4];
    #pragma unroll
    for (int ni = 0; ni < 4; ni++) Sacc[ni] = zero4;
    #pragma unroll
    for (int kk = 0; kk < 2; kk++) {
      #pragma unroll
      for (int ni = 0; ni < 4; ni++) {
        bf16x8 kF = *(const bf16x8*)(sK + swz128(ni * 16 + lo, kk * 32 + hi * 8));
        Sacc[ni] = __builtin_amdgcn_mfma_f32_16x16x32_bf16(kF, qF[kk], Sacc[ni], 0, 0, 0);
      }
    }
    const float* mB = sMaskB[cur];
    float ml = -3e38f;
    #pragma unroll
    for (int ni = 0; ni < 4; ni++) {
      #pragma unroll
      for (int jj = 0; jj < 4; jj++) {
        float sv = Sacc[ni][jj] + mB[ni * 16 + hi * 4 + jj];
        Sacc[ni][jj] = sv;
        ml = fmaxf(ml, sv);
      }
    }
    ml = fmaxf(ml, __shfl_xor(ml, 16, 64));
    ml = fmaxf(ml, __shfl_xor(ml, 32, 64));
    // ---- defer-max (T13): skip rescale when max growth <= 8 (wave-uniform decision) ----
    bool skip = __all(ml <= mrun + 8.f);
    float nm, sc;
    if (skip) { nm = mrun; sc = 1.f; }
    else      { nm = fmaxf(mrun, ml); sc = __expf(mrun - nm); }
    float rs = 0.f;   // per-lane partial sum over this lane's 16 k-slots
    bf16* sPw = sP[wv];
    #pragma unroll
    for (int ni = 0; ni < 4; ni++) {
      bf16x4 p4;
      #pragma unroll
      for (int jj = 0; jj < 4; jj++) {
        float pv = __expf(Sacc[ni][jj] - nm);
        rs += pv;
        p4[jj] = (bf16)pv;
      }
      *(bf16x4*)((char*)sPw + swz128(lo, ni * 16 + hi * 4)) = p4;
    }
    // deferred l-sum: keep lrun per-lane; cross-lane reduce happens ONCE in epilogue
    mrun = nm;
    if (skip) {
      lrun += rs;
    } else {
      lrun = lrun * sc + rs;
      float scq[4];
      #pragma unroll
      for (int jj = 0; jj < 4; jj++) scq[jj] = __shfl(sc, hi * 4 + jj, 16);
      #pragma unroll
      for (int di = 0; di < 4; di++)
        #pragma unroll
        for (int jj = 0; jj < 4; jj++) Oacc[di][jj] *= scq[jj];
    }
    #pragma unroll
    for (int kk = 0; kk < 2; kk++) {
      bf16x8 pF = *(const bf16x8*)((const char*)sPw + swz128(lo, kk * 32 + hi * 8));
      #pragma unroll
      for (int di = 0; di < 4; di++) {
        bf16x8 vF = *(const bf16x8*)(sV + swz128(di * 16 + lo, kk * 32 + hi * 8));
        Oacc[di] = __builtin_amdgcn_mfma_f32_16x16x32_bf16(pF, vF, Oacc[di], 0, 0, 0);
      }
    }
  }
  #undef ISSUE_TILE
  __syncthreads();
  // final cross-lane l reduction (4 hi-lanes of each q-row share identical sc history)
  float lsum = lrun;
  lsum += __shfl_xor(lsum, 16, 64);
  lsum += __shfl_xor(lsum, 32, 64);
  float inv = 1.f / lsum;
  float invq[4];
  #pragma unroll
  for (int jj = 0; jj < 4; jj++) invq[jj] = __shfl(inv, hi * 4 + jj, 16);
  bf16* sOut = (bf16*)sKd;
  #pragma unroll
  for (int jj = 0; jj < 4; jj++) {
    int row = wv * 16 + hi * 4 + jj;
    #pragma unroll
    for (int di = 0; di < 4; di++)
      sOut[row * 64 + di * 16 + lo] = (bf16)(Oacc[di][jj] * invq[jj]);
  }
  __syncthreads();
  bf16* dst = attnRb + (((size_t)(n * RR + r)) * RS + qsp * 128) * 64;
  #pragma unroll
  for (int it = 0; it < 2; it++) {
    int idx = tid + it * 512;
    *(uint4*)(dst + idx * 8) = *(const uint4*)(sOut + idx * 8);
  }
}

// ---------------- fused lepe + proj (8 waves): dw5x5 + from_regions + proj GEMM + residual ----------------
__global__ __launch_bounds__(512) void k_lepe3(const bf16* __restrict__ v_t, const bf16* __restrict__ attnRb,
    const float* __restrict__ lw, const float* __restrict__ lb,
    const bf16* __restrict__ pwb, const float* __restrict__ pb, float* __restrict__ xo) {
  __shared__ __align__(16) char smem[64000];
  bf16* sH = (bf16*)smem;               // 400*72 bf16 = 57600B (halo)
  float* sW = (float*)(smem + 57600);   // 25*64 f32 = 6400B
  bf16* zA = (bf16*)smem;               // overlay: 256x64 A-tile (32768B)
  bf16* sBp = (bf16*)(smem + 32768);    // overlay: 64x64 proj weights (8192B)
  int r = blockIdx.x, n = blockIdx.y;
  int rh = (r / 7) * 16, rw = (r % 7) * 16;
  int tid = threadIdx.x, lane = tid & 63, wv = tid >> 6;
  int lo = lane & 15, hi = lane >> 4;
  for (int i = tid; i < 1600; i += 512) { int c = i / 25, k = i % 25; sW[k * 64 + c] = lw[c * 25 + k]; }
  for (int g = tid; g < 3200; g += 512) {
    int pix = g >> 3, c4 = g & 7;
    int yy = pix / 20, xx = pix % 20;
    int hh = rh + yy - 2, ww = rw + xx - 2;
    uint4 d = {0, 0, 0, 0};
    if ((unsigned)hh < HW && (unsigned)ww < HW)
      d = *(const uint4*)(v_t + ((size_t)n * PP + hh * HW + ww) * 64 + c4 * 8);
    *(uint4*)((char*)sH + pix * 144 + c4 * 16) = d;
  }
  __syncthreads();
  int pixel = tid >> 1, part = tid & 1;
  int y = pixel >> 4, x = pixel & 15;
  float acc[32];
  const bf16* ar = attnRb + (((size_t)(n * RR + r)) * RS + pixel) * 64 + part * 32;
  #pragma unroll
  for (int c8 = 0; c8 < 4; c8++) {
    bf16x8 av = *(const bf16x8*)(ar + c8 * 8);
    #pragma unroll
    for (int j = 0; j < 8; j++) acc[c8 * 8 + j] = lb[part * 32 + c8 * 8 + j] + (float)av[j];
  }
  for (int t25 = 0; t25 < 25; t25++) {
    int dh = t25 / 5, dw = t25 % 5;
    int pix = (y + dh) * 20 + (x + dw);
    #pragma unroll
    for (int c8 = 0; c8 < 4; c8++) {
      bf16x8 hv = *(const bf16x8*)((const char*)sH + pix * 144 + (part * 4 + c8) * 16);
      #pragma unroll
      for (int j = 0; j < 8; j++) acc[c8 * 8 + j] += (float)hv[j] * sW[t25 * 64 + part * 32 + c8 * 8 + j];
    }
  }
  __syncthreads();   // halo reads done -> safe to overlay zA/sBp
  #pragma unroll
  for (int i = 0; i < 4; i++) {
    bf16x8 o8;
    #pragma unroll
    for (int j = 0; j < 8; j++) o8[j] = (bf16)acc[i * 8 + j];
    *(bf16x8*)((char*)zA + swz128(pixel, part * 32 + i * 8)) = o8;
  }
  { // proj weight staging: 512 uint4 one pass
    int oo = tid >> 3, q8 = tid & 7;
    uint4 d = *(const uint4*)(pwb + (size_t)oo * 64 + q8 * 8);
    *(uint4*)((char*)sBp + swz128(oo, q8 * 8)) = d;
  }
  __syncthreads();
  f32x4 acc2[2][4];
  #pragma unroll
  for (int mi = 0; mi < 2; mi++)
    #pragma unroll
    for (int ni = 0; ni < 4; ni++) acc2[mi][ni] = (f32x4){0.f, 0.f, 0.f, 0.f};
  #pragma unroll
  for (int kk = 0; kk < 2; kk++) {
    bf16x8 aF[2], bF[4];
    #pragma unroll
    for (int mi = 0; mi < 2; mi++)
      aF[mi] = *(const bf16x8*)((const char*)zA + swz128(wv * 32 + mi * 16 + lo, kk * 32 + hi * 8));
    #pragma unroll
    for (int ni = 0; ni < 4; ni++)
      bF[ni] = *(const bf16x8*)((const char*)sBp + swz128(ni * 16 + lo, kk * 32 + hi * 8));
    #pragma unroll
    for (int mi = 0; mi < 2; mi++)
      #pragma unroll
      for (int ni = 0; ni < 4; ni++)
        acc2[mi][ni] = __builtin_amdgcn_mfma_f32_16x16x32_bf16(aF[mi], bF[ni], acc2[mi][ni], 0, 0, 0);
  }
  #pragma unroll
  for (int ni = 0; ni < 4; ni++) {
    float bv = pb[ni * 16 + lo];
    #pragma unroll
    for (int mi = 0; mi < 2; mi++) {
      #pragma unroll
      for (int r2 = 0; r2 < 4; r2++) {
        int s = wv * 32 + mi * 16 + hi * 4 + r2;
        int p = (rh + (s >> 4)) * HW + rw + (s & 15);
        xo[((size_t)n * PP + p) * 64 + ni * 16 + lo] += acc2[mi][ni][r2] + bv;
      }
    }
  }
}

// ---------------- fused MLP (8 waves, 128 rows): LN2 + fc1 + gelu + fc2 + residual ----------------
__global__ __launch_bounds__(512) void k_mlp(const float* __restrict__ xin, const float* __restrict__ lng,
    const float* __restrict__ lnb, const bf16* __restrict__ w1b, const float* __restrict__ b1,
    const bf16* __restrict__ w2b, const float* __restrict__ b2, float* __restrict__ xo) {
  __shared__ bf16 sA[128 * 64];     // 16KB
  __shared__ bf16 sW[128 * 64];     // 16KB shared: W1-half (128x64) / W2-half (64x128)
  __shared__ bf16 sHh[128 * 128];   // 32KB
  int n = blockIdx.y;
  int p0 = blockIdx.x * 128;
  int tid = threadIdx.x, lane = tid & 63, wv = tid >> 6;
  int lo = lane & 15, hi = lane >> 4;
  { // fused LN staging: 4 threads per row (128 rows), 16 channels each
    int row = tid >> 2, part = tid & 3;
    const float* xp = xin + ((size_t)n * PP + p0 + row) * 64 + part * 16;
    float v[16]; float s = 0.f, sq = 0.f;
    #pragma unroll
    for (int i = 0; i < 4; i++) {
      float4 d = *(const float4*)&xp[i * 4];
      v[i*4]=d.x; v[i*4+1]=d.y; v[i*4+2]=d.z; v[i*4+3]=d.w;
      s += d.x+d.y+d.z+d.w;
      sq += d.x*d.x+d.y*d.y+d.z*d.z+d.w*d.w;
    }
    s += __shfl_xor(s, 1, 64); sq += __shfl_xor(sq, 1, 64);
    s += __shfl_xor(s, 2, 64); sq += __shfl_xor(sq, 2, 64);
    float mu = s * (1.f/64.f);
    float rstd = rsqrtf(fmaxf(sq * (1.f/64.f) - mu*mu, 0.f) + 1e-5f);
    #pragma unroll
    for (int j2 = 0; j2 < 2; j2++) {
      bf16x8 o8;
      #pragma unroll
      for (int e = 0; e < 8; e++) {
        int c = part*16 + j2*8 + e;
        o8[e] = (bf16)((v[j2*8+e] - mu) * rstd * lng[c] + lnb[c]);
      }
      *(bf16x8*)((char*)sA + swz128(row, part*16 + j2*8)) = o8;
    }
  }
  f32x4 oacc[4];
  #pragma unroll
  for (int ni = 0; ni < 4; ni++) oacc[ni] = (f32x4){0.f, 0.f, 0.f, 0.f};
  for (int half = 0; half < 2; half++) {
    // stage W1 half: 128x64 bf16 = 1024 uint4, 2/thread
    #pragma unroll
    for (int it = 0; it < 2; it++) {
      int idx = tid + it * 512;
      int oo = idx >> 3, q8 = idx & 7;
      uint4 d = *(const uint4*)(w1b + (size_t)(half * 128 + oo) * 64 + q8 * 8);
      *(uint4*)((char*)sW + swz128(oo, q8 * 8)) = d;
    }
    __syncthreads();
    f32x4 hacc[8];
    #pragma unroll
    for (int ni = 0; ni < 8; ni++) hacc[ni] = (f32x4){0.f, 0.f, 0.f, 0.f};
    #pragma unroll
    for (int kk = 0; kk < 2; kk++) {
      bf16x8 aF = *(const bf16x8*)((const char*)sA + swz128(wv * 16 + lo, kk * 32 + hi * 8));
      #pragma unroll
      for (int ni = 0; ni < 8; ni++) {
        bf16x8 bF = *(const bf16x8*)((const char*)sW + swz128(ni * 16 + lo, kk * 32 + hi * 8));
        hacc[ni] = __builtin_amdgcn_mfma_f32_16x16x32_bf16(aF, bF, hacc[ni], 0, 0, 0);
      }
    }
    #pragma unroll
    for (int ni = 0; ni < 8; ni++) {
      float bv = b1[half * 128 + ni * 16 + lo];
      #pragma unroll
      for (int r2 = 0; r2 < 4; r2++) {
        float hval = gelu_fast(hacc[ni][r2] + bv);
        *(bf16*)((char*)sHh + swzg(wv * 16 + hi * 4 + r2, ni * 16 + lo, 256)) = (bf16)hval;
      }
    }
    __syncthreads();   // fc1 reads of sW done -> safe to overwrite with W2
    // stage W2 half: 64 rows x 128 cols bf16 = 1024 uint4, 2/thread
    #pragma unroll
    for (int it = 0; it < 2; it++) {
      int idx = tid + it * 512;
      int oo = idx >> 4, q8 = idx & 15;
      uint4 d = *(const uint4*)(w2b + (size_t)oo * 256 + half * 128 + q8 * 8);
      *(uint4*)((char*)sW + swzg(oo, q8 * 8, 256)) = d;
    }
    __syncthreads();
    #pragma unroll
    for (int kk = 0; kk < 4; kk++) {
      bf16x8 aH = *(const bf16x8*)((const char*)sHh + swzg(wv * 16 + lo, kk * 32 + hi * 8, 256));
      #pragma unroll
      for (int ni = 0; ni < 4; ni++) {
        bf16x8 bF = *(const bf16x8*)((const char*)sW + swzg(ni * 16 + lo, kk * 32 + hi * 8, 256));
        oacc[ni] = __builtin_amdgcn_mfma_f32_16x16x32_bf16(aH, bF, oacc[ni], 0, 0, 0);
      }
    }
    __syncthreads();   // fc2 reads done -> next half may overwrite sW/sHh
  }
  #pragma unroll
  for (int ni = 0; ni < 4; ni++) {
    float bv = b2[ni * 16 + lo];
    #pragma unroll
    for (int r2 = 0; r2 < 4; r2++) {
      int p = p0 + wv * 16 + hi * 4 + r2;
      xo[((size_t)n * PP + p) * 64 + ni * 16 + lo] += oacc[ni][r2] + bv;
    }
  }
}

// ---------------- final untranspose: x_t[p][c] -> out[c][p] ----------------
__global__ __launch_bounds__(256) void k_untr(const float* __restrict__ x_t, float* __restrict__ out) {
  __shared__ float tile[64][68];
  int n = blockIdx.y; int p0 = blockIdx.x * 64;
  int tid = threadIdx.x;
  #pragma unroll
  for (int it = 0; it < 4; it++) {
    int g = tid + it * 256;
    int row = g >> 4, q = g & 15;
    float4 d = *(const float4*)&x_t[((size_t)n * PP + p0 + row) * 64 + q * 4];
    *(float4*)&tile[row][q * 4] = d;
  }
  __syncthreads();
  #pragma unroll
  for (int it = 0; it < 4; it++) {
    int g = tid + it * 256;
    int c = g >> 4, q = g & 15;
    float4 v;
    v.x = tile[q * 4 + 0][c]; v.y = tile[q * 4 + 1][c];
    v.z = tile[q * 4 + 2][c]; v.w = tile[q * 4 + 3][c];
    *(float4*)&out[((size_t)(n * 64 + c)) * PP + p0 + q * 4] = v;
  }
}

extern "C" void kernel_launch(void* const* d_in, const int* in_sizes, int n_in,
                              void* d_out, int out_size, void* d_ws, size_t ws_size,
                              hipStream_t stream) {
  const float* ex0 = (const float*)d_in[0];
  const float* ex  = (const float*)d_in[1];
  const float* img = (const float*)d_in[2];
  const float* pre = (const float*)d_in[3];
  const float* c0w = (const float*)d_in[4];
  const float* c0b = (const float*)d_in[5];
  const float* ln1g = (const float*)d_in[6];
  const float* ln1b = (const float*)d_in[7];
  const float* ln2g = (const float*)d_in[8];
  const float* ln2b = (const float*)d_in[9];
  const float* qkvw = (const float*)d_in[10];
  const float* qkvb = (const float*)d_in[11];
  const float* lw = (const float*)d_in[12];
  const float* lb = (const float*)d_in[13];
  const float* pw = (const float*)d_in[14];
  const float* pb = (const float*)d_in[15];
  const float* f1w = (const float*)d_in[16];
  const float* f1b = (const float*)d_in[17];
  const float* f2w = (const float*)d_in[18];
  const float* f2b = (const float*)d_in[19];

  float* W = (float*)d_ws;
  size_t o = 0;
  bf16* xct = (bf16*)(W + o);  o += (size_t)BB * GP * CK / 2;
  float* x_t  = W + o;         o += 3211264;
  bf16* attnRb = (bf16*)(W + o); o += 1605632;
  bf16* v_t  = (bf16*)(W + o); o += 1605632;
  bf16* qR   = (bf16*)(W + o); o += 1605632;
  bf16* kR   = (bf16*)(W + o); o += 1605632;
  bf16* vT   = (bf16*)(W + o); o += 1605632;
  float* qd = W + o;           o += 12544;
  float* kd = W + o;           o += 12544;
  float* maskr = W + o;        o += 50176;
  bf16* wTb = (bf16*)(W + o);  o += 46080;
  bf16* qkvwb = (bf16*)(W + o); o += 24576;   // 4*192*64 bf16
  bf16* pwb   = (bf16*)(W + o); o += 8192;    // 4*64*64
  bf16* f1wb  = (bf16*)(W + o); o += 32768;   // 4*256*64
  bf16* f2wb  = (bf16*)(W + o); o += 32768;   // 4*64*256
  int* gidx = (int*)(W + o);   o += 784;

  k_ring<<<dim3((BB * 452 * 20 + 255) / 256), dim3(256), 0, stream>>>(xct);
  k_prep2<<<dim3(196, BB), dim3(256), 0, stream>>>(ex0, ex, img, pre, xct, maskr);
  k_wt2<<<dim3(360), dim3(256), 0, stream>>>(c0w, wTb);
  k_wcvt<<<dim3((49152 + 16384 + 65536 + 65536 + 255) / 256), dim3(256), 0, stream>>>(
      qkvw, qkvwb, 49152, pw, pwb, 16384, f1w, f1wb, 65536, f2w, f2wb, 65536);
  k_conv0m<<<dim3(98, BB), dim3(256), 0, stream>>>(xct, wTb, c0b, x_t);
  for (int i = 0; i < 4; i++) {
    k_qkvr<<<dim3(RR, BB), dim3(512), 0, stream>>>(x_t, ln1g + i * 64, ln1b + i * 64,
        qkvwb + (size_t)i * 192 * 64, qkvb + i * 192, qR, kR, v_t, vT, qd, kd);
    k_topk<<<dim3(RR, BB), dim3(64), 0, stream>>>(qd, kd, gidx);
    k_attn<<<dim3(BB * RR * 2), dim3(512), 0, stream>>>(qR, kR, vT, maskr, gidx, attnRb);
    k_lepe3<<<dim3(RR, BB), dim3(512), 0, stream>>>(v_t, attnRb, lw + (size_t)i * 64 * 25, lb + i * 64,
        pwb + (size_t)i * 64 * 64, pb + i * 64, x_t);
    k_mlp<<<dim3(98, BB), dim3(512), 0, stream>>>(x_t, ln2g + i * 64, ln2b + i * 64,
        f1wb + (size_t)i * 256 * 64, f1b + i * 256, f2wb + (size_t)i * 64 * 256, f2b + i * 64, x_t);
  }
  k_untr<<<dim3(196, BB), dim3(256), 0, stream>>>(x_t, (float*)d_out);
}